// Round 1
// baseline (633.024 us; speedup 1.0000x reference)
//
#include <hip/hip_runtime.h>
#include <stdint.h>
#include <math.h>

// Problem constants (N, Cin, Cout fixed by setup_inputs)
#define NROWS 65536
#define CIN   1024
#define COUT  1024
#define KW    16          // 1024 bits / 64 bits per u64
#define BN_EPS 1e-5

// Workspace layout (bytes):
//   psum  : double[64][1024]   @ 0          (524288)
//   psq   : double[64][1024]   @ 524288     (524288)
//   mu    : float[1024]        @ 1048576    (4096)
//   inv   : float[1024]        @ 1052672    (4096)
//   Wbits : u64[1024][16]      @ 1114112    (131072)
//   Abits : u64[65536][16]     @ 1310720    (8388608)
// total ~9.25 MB
static constexpr size_t OFF_PSUM = 0;
static constexpr size_t OFF_PSQ  = 524288;
static constexpr size_t OFF_MU   = 1048576;
static constexpr size_t OFF_INV  = 1048576 + 4096;
static constexpr size_t OFF_WB   = 1048576 + 65536;
static constexpr size_t OFF_AB   = 1310720;

// K1: per-column partial sums over 1024-row chunks, fp64 accumulation.
// grid (CIN/256, NROWS/1024) = (4, 64), block 256. Coalesced: consecutive
// threads = consecutive columns.
__global__ __launch_bounds__(256) void k_stats_partial(
    const float* __restrict__ x, double* __restrict__ psum, double* __restrict__ psq) {
  int c  = blockIdx.x * 256 + threadIdx.x;
  size_t r0 = (size_t)blockIdx.y * 1024;
  const float* p = x + r0 * CIN + c;
  double s = 0.0, q = 0.0;
  for (int r = 0; r < 1024; ++r) {
    double v = (double)p[(size_t)r * CIN];
    s += v;
    q = fma(v, v, q);
  }
  psum[(size_t)blockIdx.y * CIN + c] = s;
  psq [(size_t)blockIdx.y * CIN + c] = q;
}

// K2: finalize mean / rsqrt(var+eps) per channel. grid 4, block 256.
__global__ __launch_bounds__(256) void k_stats_final(
    const double* __restrict__ psum, const double* __restrict__ psq,
    float* __restrict__ mu, float* __restrict__ inv) {
  int c = blockIdx.x * 256 + threadIdx.x;
  double s = 0.0, q = 0.0;
  for (int p = 0; p < 64; ++p) {
    s += psum[(size_t)p * CIN + c];
    q += psq [(size_t)p * CIN + c];
  }
  double mean = s / (double)NROWS;
  double var  = q / (double)NROWS - mean * mean;  // population var (ddof=0)
  mu[c]  = (float)mean;
  inv[c] = (float)(1.0 / sqrt(var + (double)BN_EPS));
}

// K3: binarize normalized activations into bit rows via wave ballot.
// One block per row; 4 waves x 4 iterations cover 1024 columns.
__global__ __launch_bounds__(256) void k_binarize_x(
    const float* __restrict__ x, const float* __restrict__ mu,
    const float* __restrict__ inv, const float* __restrict__ gamma,
    const float* __restrict__ beta, uint64_t* __restrict__ Abits) {
  int n    = blockIdx.x;
  int tid  = threadIdx.x;
  int lane = tid & 63;
  int wave = tid >> 6;
  const float* row = x + (size_t)n * CIN;
  #pragma unroll
  for (int j = 0; j < 4; ++j) {
    int c = j * 256 + tid;
    // match reference op order: ((x - mu) * rsqrt) * gamma + beta
    float xh = ((row[c] - mu[c]) * inv[c]) * gamma[c] + beta[c];
    uint64_t m = __ballot(xh >= 0.0f);  // bit=1 <=> +1
    if (lane == 0) Abits[(size_t)n * KW + j * 4 + wave] = m;
  }
}

// K4: binarize W rows into bits. One block per output channel.
__global__ __launch_bounds__(256) void k_binarize_w(
    const float* __restrict__ W, uint64_t* __restrict__ Wbits) {
  int o    = blockIdx.x;
  int tid  = threadIdx.x;
  int lane = tid & 63;
  int wave = tid >> 6;
  const float* row = W + (size_t)o * CIN;
  #pragma unroll
  for (int j = 0; j < 4; ++j) {
    int c = j * 256 + tid;
    uint64_t m = __ballot(row[c] >= 0.0f);
    if (lane == 0) Wbits[(size_t)o * KW + j * 4 + wave] = m;
  }
}

// K5: XNOR-popcount GEMM + fused bias/scale/PReLU epilogue.
// grid (COUT/256, NROWS/64), block 256. Each thread owns one output column o
// (B bits in 32 VGPRs, reused for 64 rows); A-row words are wave-uniform
// (scalar-load / broadcast path). Stores: 64 lanes -> 256B contiguous.
__global__ __launch_bounds__(256) void k_bingemm(
    const uint64_t* __restrict__ Abits, const uint64_t* __restrict__ Wbits,
    const float* __restrict__ bias, const float* __restrict__ scale,
    const float* __restrict__ alphaPtr, float* __restrict__ out) {
  int o = blockIdx.x * 256 + threadIdx.x;

  uint64_t B[KW];
  #pragma unroll
  for (int j = 0; j < KW; ++j) B[j] = Wbits[(size_t)o * KW + j];

  float alpha = alphaPtr[0];
  float sc = scale[o];
  float c2 = -2.0f * sc;                    // y = (K - 2d + b)*sc = c1 + c2*d
  float c1 = (1024.0f + bias[o]) * sc;

  int n0 = blockIdx.y * 64;
  for (int r = 0; r < 64; ++r) {
    int n = n0 + r;
    const uint64_t* A = Abits + (size_t)n * KW;  // wave-uniform address
    int d0 = 0, d1 = 0, d2 = 0, d3 = 0;
    #pragma unroll
    for (int j = 0; j < KW; j += 4) {
      d0 += __popcll(A[j + 0] ^ B[j + 0]);
      d1 += __popcll(A[j + 1] ^ B[j + 1]);
      d2 += __popcll(A[j + 2] ^ B[j + 2]);
      d3 += __popcll(A[j + 3] ^ B[j + 3]);
    }
    int d = (d0 + d1) + (d2 + d3);
    float y = fmaf((float)d, c2, c1);
    out[(size_t)n * COUT + o] = y > 0.0f ? y : alpha * y;
  }
}

extern "C" void kernel_launch(void* const* d_in, const int* in_sizes, int n_in,
                              void* d_out, int out_size, void* d_ws, size_t ws_size,
                              hipStream_t stream) {
  const float* x     = (const float*)d_in[0];
  const float* gamma = (const float*)d_in[1];
  const float* beta  = (const float*)d_in[2];
  const float* W     = (const float*)d_in[3];
  const float* b     = (const float*)d_in[4];
  const float* scale = (const float*)d_in[5];
  const float* alpha = (const float*)d_in[6];
  float* out = (float*)d_out;

  char* ws = (char*)d_ws;
  double*   psum  = (double*)(ws + OFF_PSUM);
  double*   psq   = (double*)(ws + OFF_PSQ);
  float*    mu    = (float*)(ws + OFF_MU);
  float*    inv   = (float*)(ws + OFF_INV);
  uint64_t* Wbits = (uint64_t*)(ws + OFF_WB);
  uint64_t* Abits = (uint64_t*)(ws + OFF_AB);

  k_stats_partial<<<dim3(CIN / 256, NROWS / 1024), 256, 0, stream>>>(x, psum, psq);
  k_stats_final<<<dim3(CIN / 256), 256, 0, stream>>>(psum, psq, mu, inv);
  k_binarize_w<<<dim3(COUT), 256, 0, stream>>>(W, Wbits);
  k_binarize_x<<<dim3(NROWS), 256, 0, stream>>>(x, mu, inv, gamma, beta, Abits);
  k_bingemm<<<dim3(COUT / 256, NROWS / 64), 256, 0, stream>>>(
      Abits, Wbits, b, scale, alpha, out);
}

// Round 2
// 607.351 us; speedup vs baseline: 1.0423x; 1.0423x over previous
//
#include <hip/hip_runtime.h>
#include <stdint.h>
#include <math.h>

// Problem constants (fixed by setup_inputs)
#define NROWS 65536
#define CIN   1024
#define COUT  1024
#define BN_EPS 1e-5

// Bit packing: permuted-but-consistent mapping. For row segment handled by
// wave w (columns 256w..256w+255), thread tid=64w+L computes columns
// 4*tid..4*tid+3 via float4; ballot k (k=0..3) produces word w*4+k whose bit
// L corresponds to column 256w+4L+k. A-rows and W-rows use the IDENTICAL
// packing, so XOR+popcount is unaffected by the permutation.

// Workspace layout (bytes) — ws_size is 1 GiB, we use 14 MB:
static constexpr size_t OFF_PSUM = 0;                      // double[256][1024] = 2 MB
static constexpr size_t OFF_PSQ  = 2u * 1024 * 1024;       // double[256][1024] = 2 MB
static constexpr size_t OFF_MU   = 4u * 1024 * 1024;       // float[1024]
static constexpr size_t OFF_INV  = 4u * 1024 * 1024 + 4096;
static constexpr size_t OFF_WB   = 5u * 1024 * 1024;       // u64[1024][16] = 128 KB
static constexpr size_t OFF_AB   = 6u * 1024 * 1024;       // u64[65536][16] = 8 MB

typedef uint64_t u64x2 __attribute__((ext_vector_type(2)));
typedef uint32_t u32x4 __attribute__((ext_vector_type(4)));
// Constant-address-space pointer: uniform loads through AS(4) select the
// scalar path (s_load) on gfx950; if divergence analysis disagrees it falls
// back to global_load — correct either way.
typedef const u32x4 __attribute__((address_space(4)))* c4p;

// ---------------------------------------------------------------------------
// K1: per-column partial sums over 256-row chunks, fp64 accumulation.
// grid 256 blocks (one per chunk), block 256 threads (4 cols each via float4).
// Unroll 8 rows -> 8 outstanding 1KB wave-loads for HBM saturation.
__global__ __launch_bounds__(256) void k_stats_partial(
    const float* __restrict__ x, double* __restrict__ psum, double* __restrict__ psq) {
  int tid = threadIdx.x;
  size_t r0 = (size_t)blockIdx.x * 256;
  const float4* xp = (const float4*)x + r0 * 256 + tid;
  double s0 = 0, s1 = 0, s2 = 0, s3 = 0;
  double q0 = 0, q1 = 0, q2 = 0, q3 = 0;
  for (int r = 0; r < 256; r += 8) {
    float4 v[8];
#pragma unroll
    for (int u = 0; u < 8; ++u) v[u] = xp[(size_t)(r + u) * 256];
#pragma unroll
    for (int u = 0; u < 8; ++u) {
      double a = (double)v[u].x, b = (double)v[u].y;
      double c = (double)v[u].z, d = (double)v[u].w;
      s0 += a; q0 = fma(a, a, q0);
      s1 += b; q1 = fma(b, b, q1);
      s2 += c; q2 = fma(c, c, q2);
      s3 += d; q3 = fma(d, d, q3);
    }
  }
  size_t base = (size_t)blockIdx.x * CIN + (size_t)tid * 4;
  double2* ps = (double2*)(psum + base);
  ps[0] = make_double2(s0, s1);
  ps[1] = make_double2(s2, s3);
  double2* pq = (double2*)(psq + base);
  pq[0] = make_double2(q0, q1);
  pq[1] = make_double2(q2, q3);
}

// K2: reduce 256 chunk-partials per column -> mu, rsqrt(var+eps).
// grid 16 blocks (64 cols each), block 256: 4 wave-groups x 64 chunks, LDS combine.
__global__ __launch_bounds__(256) void k_stats_final(
    const double* __restrict__ psum, const double* __restrict__ psq,
    float* __restrict__ mu, float* __restrict__ inv) {
  __shared__ double sd[4][64];
  __shared__ double sq[4][64];
  int tid = threadIdx.x, lane = tid & 63, g = tid >> 6;
  int col = blockIdx.x * 64 + lane;
  double s = 0, q = 0;
  for (int i = 0; i < 64; ++i) {
    size_t chunk = (size_t)(g * 64 + i);
    s += psum[chunk * CIN + col];
    q += psq [chunk * CIN + col];
  }
  sd[g][lane] = s;
  sq[g][lane] = q;
  __syncthreads();
  if (g == 0) {
    s = sd[0][lane] + sd[1][lane] + sd[2][lane] + sd[3][lane];
    q = sq[0][lane] + sq[1][lane] + sq[2][lane] + sq[3][lane];
    double mean = s / (double)NROWS;
    double var  = q / (double)NROWS - mean * mean;  // population var (ddof=0)
    mu[col]  = (float)mean;
    inv[col] = (float)(1.0 / sqrt(var + (double)BN_EPS));
  }
}

// K3: binarize normalized activations -> bit rows. grid 8192 (8 rows/block),
// block 256. Per-channel constants hoisted out of the row loop. Exact
// reference op order: ((x - mu) * inv) * gamma + beta.
__global__ __launch_bounds__(256) void k_binarize_x(
    const float* __restrict__ x, const float* __restrict__ mu,
    const float* __restrict__ inv, const float* __restrict__ gamma,
    const float* __restrict__ beta, uint64_t* __restrict__ Abits) {
  int tid = threadIdx.x, lane = tid & 63, wv = tid >> 6;
  float4 M  = ((const float4*)mu)[tid];
  float4 I  = ((const float4*)inv)[tid];
  float4 G  = ((const float4*)gamma)[tid];
  float4 Bt = ((const float4*)beta)[tid];
  size_t n0 = (size_t)blockIdx.x * 8;
  const float4* xp = (const float4*)x + n0 * 256 + tid;
  for (int r = 0; r < 8; ++r) {
    float4 v = xp[(size_t)r * 256];
    float h0 = ((v.x - M.x) * I.x) * G.x + Bt.x;
    float h1 = ((v.y - M.y) * I.y) * G.y + Bt.y;
    float h2 = ((v.z - M.z) * I.z) * G.z + Bt.z;
    float h3 = ((v.w - M.w) * I.w) * G.w + Bt.w;
    uint64_t b0 = __ballot(h0 >= 0.0f);
    uint64_t b1 = __ballot(h1 >= 0.0f);
    uint64_t b2 = __ballot(h2 >= 0.0f);
    uint64_t b3 = __ballot(h3 >= 0.0f);
    uint64_t t0 = b0, t1 = b1;
    if (lane == 1) { t0 = b2; t1 = b3; }
    if (lane < 2) {
      u64x2 val; val.x = t0; val.y = t1;
      *(u64x2*)(Abits + (n0 + r) * 16 + wv * 4 + lane * 2) = val;
    }
  }
}

// K4: binarize W rows -> bits, identical packing. grid 128 (8 rows/block).
__global__ __launch_bounds__(256) void k_binarize_w(
    const float* __restrict__ W, uint64_t* __restrict__ Wbits) {
  int tid = threadIdx.x, lane = tid & 63, wv = tid >> 6;
  size_t o0 = (size_t)blockIdx.x * 8;
  const float4* wp = (const float4*)W + o0 * 256 + tid;
  for (int r = 0; r < 8; ++r) {
    float4 v = wp[(size_t)r * 256];
    uint64_t b0 = __ballot(v.x >= 0.0f);
    uint64_t b1 = __ballot(v.y >= 0.0f);
    uint64_t b2 = __ballot(v.z >= 0.0f);
    uint64_t b3 = __ballot(v.w >= 0.0f);
    uint64_t t0 = b0, t1 = b1;
    if (lane == 1) { t0 = b2; t1 = b3; }
    if (lane < 2) {
      u64x2 val; val.x = t0; val.y = t1;
      *(u64x2*)(Wbits + (o0 + r) * 16 + wv * 4 + lane * 2) = val;
    }
  }
}

// K5: XNOR-popcount GEMM + fused bias/scale/PReLU.
// grid (COUT/256, NROWS/64), block 256. Thread owns output column o; B bits
// in 32 VGPRs reused across 64 rows. A-row words are wave-uniform and loaded
// through AS(4) -> scalar s_load path (no per-lane VMEM broadcast storm).
__global__ __launch_bounds__(256) void k_bingemm(
    const uint32_t* __restrict__ Abits, const uint32_t* __restrict__ Wbits,
    const float* __restrict__ bias, const float* __restrict__ scale,
    const float* __restrict__ alphaPtr, float* __restrict__ out) {
  int tid = threadIdx.x;
  int o = blockIdx.x * 256 + tid;

  u32x4 B[8];
  const u32x4* wp = (const u32x4*)(Wbits + (size_t)o * 32);
#pragma unroll
  for (int j = 0; j < 8; ++j) B[j] = wp[j];

  float alpha = alphaPtr[0];
  float sc = scale[o];
  float c2 = -2.0f * sc;                    // y = (K - 2d + b)*sc = c1 + c2*d
  float c1 = (1024.0f + bias[o]) * sc;

  size_t n0 = (size_t)blockIdx.y * 64;
  c4p Ar = (c4p)(uintptr_t)(Abits + n0 * 32);
  float* op = out + n0 * COUT + o;

  for (int r = 0; r < 64; ++r) {
    int d0 = 0, d1 = 0, d2 = 0, d3 = 0;
#pragma unroll
    for (int j = 0; j < 8; ++j) {
      u32x4 a = Ar[j];
      d0 += __builtin_popcount(a.x ^ B[j].x);
      d1 += __builtin_popcount(a.y ^ B[j].y);
      d2 += __builtin_popcount(a.z ^ B[j].z);
      d3 += __builtin_popcount(a.w ^ B[j].w);
    }
    Ar += 8;
    int d = (d0 + d1) + (d2 + d3);
    float y = fmaf((float)d, c2, c1);
    *op = y > 0.0f ? y : alpha * y;
    op += COUT;
  }
}

extern "C" void kernel_launch(void* const* d_in, const int* in_sizes, int n_in,
                              void* d_out, int out_size, void* d_ws, size_t ws_size,
                              hipStream_t stream) {
  const float* x     = (const float*)d_in[0];
  const float* gamma = (const float*)d_in[1];
  const float* beta  = (const float*)d_in[2];
  const float* W     = (const float*)d_in[3];
  const float* b     = (const float*)d_in[4];
  const float* scale = (const float*)d_in[5];
  const float* alpha = (const float*)d_in[6];
  float* out = (float*)d_out;

  char* ws = (char*)d_ws;
  double*   psum  = (double*)(ws + OFF_PSUM);
  double*   psq   = (double*)(ws + OFF_PSQ);
  float*    mu    = (float*)(ws + OFF_MU);
  float*    inv   = (float*)(ws + OFF_INV);
  uint64_t* Wbits = (uint64_t*)(ws + OFF_WB);
  uint64_t* Abits = (uint64_t*)(ws + OFF_AB);

  k_stats_partial<<<dim3(NROWS / 256), 256, 0, stream>>>(x, psum, psq);
  k_stats_final<<<dim3(CIN / 64), 256, 0, stream>>>(psum, psq, mu, inv);
  k_binarize_w<<<dim3(COUT / 8), 256, 0, stream>>>(W, Wbits);
  k_binarize_x<<<dim3(NROWS / 8), 256, 0, stream>>>(x, mu, inv, gamma, beta, Abits);
  k_bingemm<<<dim3(COUT / 256, NROWS / 64), 256, 0, stream>>>(
      (const uint32_t*)Abits, (const uint32_t*)Wbits, b, scale, alpha, out);
}

// Round 3
// 591.497 us; speedup vs baseline: 1.0702x; 1.0268x over previous
//
#include <hip/hip_runtime.h>
#include <stdint.h>
#include <math.h>

// Problem constants (fixed by setup_inputs)
#define NROWS 65536
#define CIN   1024
#define COUT  1024
#define BN_EPS 1e-5

// Bit packing (verified absmax=0 in round 2): for wave w (columns
// 256w..256w+255), thread tid=64w+L handles columns 4*tid..4*tid+3 via
// float4; ballot k (k=0..3) produces word w*4+k whose bit L is column
// 256w+4L+k. A and W use the IDENTICAL packing so XOR+popcount is exact.

// Workspace layout (bytes), ws_size = 1 GiB, we use ~18 MB:
static constexpr size_t OFF_PSUM = 0;                        // double[512][1024] = 4 MB
static constexpr size_t OFF_PSQ  = 4ull * 1024 * 1024;       // double[512][1024] = 4 MB
static constexpr size_t OFF_MU   = 8ull * 1024 * 1024;       // float[1024]
static constexpr size_t OFF_INV  = 8ull * 1024 * 1024 + 4096;
static constexpr size_t OFF_WB   = 9ull * 1024 * 1024;       // u64[1024][16] = 128 KB
static constexpr size_t OFF_AB   = 10ull * 1024 * 1024;      // u64[65536][16] = 8 MB

typedef uint64_t u64x2 __attribute__((ext_vector_type(2)));
typedef uint32_t u32x4 __attribute__((ext_vector_type(4)));

// ---------------------------------------------------------------------------
// K1: per-column partial sums over 128-row chunks, fp64 accumulation.
// grid 512 (2 blocks/CU, 8 waves/CU), block 256 (4 cols each via float4).
// 8 rows unrolled -> 8 outstanding 1KB wave-loads for HBM saturation.
__global__ __launch_bounds__(256) void k_stats_partial(
    const float* __restrict__ x, double* __restrict__ psum, double* __restrict__ psq) {
  int tid = threadIdx.x;
  size_t r0 = (size_t)blockIdx.x * 128;
  const float4* xp = (const float4*)x + r0 * 256 + tid;
  double s0 = 0, s1 = 0, s2 = 0, s3 = 0;
  double q0 = 0, q1 = 0, q2 = 0, q3 = 0;
  for (int r = 0; r < 128; r += 8) {
    float4 v[8];
#pragma unroll
    for (int u = 0; u < 8; ++u) v[u] = xp[(size_t)(r + u) * 256];
#pragma unroll
    for (int u = 0; u < 8; ++u) {
      double a = (double)v[u].x, b = (double)v[u].y;
      double c = (double)v[u].z, d = (double)v[u].w;
      s0 += a; q0 = fma(a, a, q0);
      s1 += b; q1 = fma(b, b, q1);
      s2 += c; q2 = fma(c, c, q2);
      s3 += d; q3 = fma(d, d, q3);
    }
  }
  size_t base = (size_t)blockIdx.x * CIN + (size_t)tid * 4;
  double2* ps = (double2*)(psum + base);
  ps[0] = make_double2(s0, s1);
  ps[1] = make_double2(s2, s3);
  double2* pq = (double2*)(psq + base);
  pq[0] = make_double2(q0, q1);
  pq[1] = make_double2(q2, q3);
}

// K2: reduce 512 chunk-partials per column -> mu, rsqrt(var+eps).
// grid 64 blocks; block 256 = 16 cols x 16 groups of 32 chunks; LDS combine.
__global__ __launch_bounds__(256) void k_stats_final(
    const double* __restrict__ psum, const double* __restrict__ psq,
    float* __restrict__ mu, float* __restrict__ inv) {
  __shared__ double sd[16][16];
  __shared__ double sq[16][16];
  int tid = threadIdx.x;
  int cl = tid & 15;          // column within block
  int g  = tid >> 4;          // chunk group 0..15
  int col = blockIdx.x * 16 + cl;
  double s = 0, q = 0;
  for (int i = 0; i < 32; ++i) {
    size_t chunk = (size_t)(g * 32 + i);
    s += psum[chunk * CIN + col];
    q += psq [chunk * CIN + col];
  }
  sd[g][cl] = s;
  sq[g][cl] = q;
  __syncthreads();
  if (tid < 16) {
    s = 0; q = 0;
#pragma unroll
    for (int i = 0; i < 16; ++i) { s += sd[i][tid]; q += sq[i][tid]; }
    double mean = s / (double)NROWS;
    double var  = q / (double)NROWS - mean * mean;  // population var (ddof=0)
    int c = blockIdx.x * 16 + tid;
    mu[c]  = (float)mean;
    inv[c] = (float)(1.0 / sqrt(var + (double)BN_EPS));
  }
}

// K3: binarize normalized activations -> bit rows. grid 8192 (8 rows/block),
// block 256, float4 loads, per-channel constants hoisted out of the row loop.
// Exact reference op order: ((x - mu) * inv) * gamma + beta.
__global__ __launch_bounds__(256) void k_binarize_x(
    const float* __restrict__ x, const float* __restrict__ mu,
    const float* __restrict__ inv, const float* __restrict__ gamma,
    const float* __restrict__ beta, uint64_t* __restrict__ Abits) {
  int tid = threadIdx.x, lane = tid & 63, wv = tid >> 6;
  float4 M  = ((const float4*)mu)[tid];
  float4 I  = ((const float4*)inv)[tid];
  float4 G  = ((const float4*)gamma)[tid];
  float4 Bt = ((const float4*)beta)[tid];
  size_t n0 = (size_t)blockIdx.x * 8;
  const float4* xp = (const float4*)x + n0 * 256 + tid;
  for (int r = 0; r < 8; ++r) {
    float4 v = xp[(size_t)r * 256];
    float h0 = ((v.x - M.x) * I.x) * G.x + Bt.x;
    float h1 = ((v.y - M.y) * I.y) * G.y + Bt.y;
    float h2 = ((v.z - M.z) * I.z) * G.z + Bt.z;
    float h3 = ((v.w - M.w) * I.w) * G.w + Bt.w;
    uint64_t b0 = __ballot(h0 >= 0.0f);
    uint64_t b1 = __ballot(h1 >= 0.0f);
    uint64_t b2 = __ballot(h2 >= 0.0f);
    uint64_t b3 = __ballot(h3 >= 0.0f);
    uint64_t t0 = b0, t1 = b1;
    if (lane == 1) { t0 = b2; t1 = b3; }
    if (lane < 2) {
      u64x2 val; val.x = t0; val.y = t1;
      *(u64x2*)(Abits + (n0 + r) * 16 + wv * 4 + lane * 2) = val;
    }
  }
}

// K4: binarize W rows -> bits, identical packing. grid 128 (8 rows/block).
__global__ __launch_bounds__(256) void k_binarize_w(
    const float* __restrict__ W, uint64_t* __restrict__ Wbits) {
  int tid = threadIdx.x, lane = tid & 63, wv = tid >> 6;
  size_t o0 = (size_t)blockIdx.x * 8;
  const float4* wp = (const float4*)W + o0 * 256 + tid;
  for (int r = 0; r < 8; ++r) {
    float4 v = wp[(size_t)r * 256];
    uint64_t b0 = __ballot(v.x >= 0.0f);
    uint64_t b1 = __ballot(v.y >= 0.0f);
    uint64_t b2 = __ballot(v.z >= 0.0f);
    uint64_t b3 = __ballot(v.w >= 0.0f);
    uint64_t t0 = b0, t1 = b1;
    if (lane == 1) { t0 = b2; t1 = b3; }
    if (lane < 2) {
      u64x2 val; val.x = t0; val.y = t1;
      *(u64x2*)(Wbits + (o0 + r) * 16 + wv * 4 + lane * 2) = val;
    }
  }
}

// K5: XNOR-popcount GEMM + fused bias/scale/PReLU.
// grid (COUT/256, NROWS/128), block 256. Thread owns output column o; its
// 1024 B-bits live in 32 VGPRs, reused across 128 rows. The A-tile
// (128 rows x 128 B = 16 KB) is staged in LDS once per block with coalesced
// dwordx4 loads; compute reads it as wave-uniform same-address broadcasts
// (conflict-free). No dependence on scalar-load selection heuristics.
#define K5_ROWS 128
__global__ __launch_bounds__(256) void k_bingemm(
    const uint32_t* __restrict__ Abits, const uint32_t* __restrict__ Wbits,
    const float* __restrict__ bias, const float* __restrict__ scale,
    const float* __restrict__ alphaPtr, float* __restrict__ out) {
  __shared__ uint32_t tile[K5_ROWS * 32];  // 16 KB
  int tid = threadIdx.x;
  int o = blockIdx.x * 256 + tid;
  size_t n0 = (size_t)blockIdx.y * K5_ROWS;

  // Stage A-tile: 4096 u32 = 1024 u32x4; 256 threads x 4 iterations.
  {
    const u32x4* src = (const u32x4*)(Abits + n0 * 32);
    u32x4* dst = (u32x4*)tile;
#pragma unroll
    for (int i = 0; i < 4; ++i) dst[i * 256 + tid] = src[i * 256 + tid];
  }

  // B-column bits into 32 VGPRs.
  u32x4 B[8];
  const u32x4* wp = (const u32x4*)(Wbits + (size_t)o * 32);
#pragma unroll
  for (int j = 0; j < 8; ++j) B[j] = wp[j];

  float alpha = alphaPtr[0];
  float sc = scale[o];
  float c2 = -2.0f * sc;                    // y = (K - 2d + b)*sc = c1 + c2*d
  float c1 = (1024.0f + bias[o]) * sc;

  __syncthreads();

  float* op = out + n0 * COUT + o;
  for (int r = 0; r < K5_ROWS; ++r) {
    const u32x4* A = (const u32x4*)(tile + r * 32);
    int d0 = 0, d1 = 0, d2 = 0, d3 = 0;
#pragma unroll
    for (int j = 0; j < 8; ++j) {
      u32x4 a = A[j];
      d0 += __builtin_popcount(a.x ^ B[j].x);
      d1 += __builtin_popcount(a.y ^ B[j].y);
      d2 += __builtin_popcount(a.z ^ B[j].z);
      d3 += __builtin_popcount(a.w ^ B[j].w);
    }
    int d = (d0 + d1) + (d2 + d3);
    float y = fmaf((float)d, c2, c1);
    *op = y > 0.0f ? y : alpha * y;
    op += COUT;
  }
}

extern "C" void kernel_launch(void* const* d_in, const int* in_sizes, int n_in,
                              void* d_out, int out_size, void* d_ws, size_t ws_size,
                              hipStream_t stream) {
  const float* x     = (const float*)d_in[0];
  const float* gamma = (const float*)d_in[1];
  const float* beta  = (const float*)d_in[2];
  const float* W     = (const float*)d_in[3];
  const float* b     = (const float*)d_in[4];
  const float* scale = (const float*)d_in[5];
  const float* alpha = (const float*)d_in[6];
  float* out = (float*)d_out;

  char* ws = (char*)d_ws;
  double*   psum  = (double*)(ws + OFF_PSUM);
  double*   psq   = (double*)(ws + OFF_PSQ);
  float*    mu    = (float*)(ws + OFF_MU);
  float*    inv   = (float*)(ws + OFF_INV);
  uint64_t* Wbits = (uint64_t*)(ws + OFF_WB);
  uint64_t* Abits = (uint64_t*)(ws + OFF_AB);

  k_stats_partial<<<dim3(NROWS / 128), 256, 0, stream>>>(x, psum, psq);
  k_stats_final<<<dim3(CIN / 16), 256, 0, stream>>>(psum, psq, mu, inv);
  k_binarize_w<<<dim3(COUT / 8), 256, 0, stream>>>(W, Wbits);
  k_binarize_x<<<dim3(NROWS / 8), 256, 0, stream>>>(x, mu, inv, gamma, beta, Abits);
  k_bingemm<<<dim3(COUT / 256, NROWS / K5_ROWS), 256, 0, stream>>>(
      (const uint32_t*)Abits, (const uint32_t*)Wbits, b, scale, alpha, out);
}